// Round 1
// baseline (1064.972 us; speedup 1.0000x reference)
//
#include <hip/hip_runtime.h>

// Swin shifted-window attention, fused single kernel, fp32 baseline.
// B=16 H=W=128 C=96 NH=3 d=32 WS=8 SS=4 -> L=64, 256 windows, 4096 blocks.
// No padding (128%8==0); shift always active; mask computed arithmetically.

#define STRX 97   // LDS row stride for [64][96]-ish row-major tiles (2-way bank alias = free)
#define STRT 68   // LDS row stride for transposed k/v [96][64] (16B-aligned for float4 reads)

__global__ __launch_bounds__(256, 2) void swin_fused(
    const float* __restrict__ x,
    const float* __restrict__ qkv_w,
    const float* __restrict__ qkv_b,
    const float* __restrict__ proj_w,
    const float* __restrict__ proj_b,
    const float* __restrict__ rel_bias,
    float* __restrict__ out)
{
    __shared__ float xs[64 * STRX];  // x window; later attention output   (24.25 KB)
    __shared__ float kt[96 * STRT];  // k transposed [c][row]; later proj-out staging (25.5 KB)
    __shared__ float vt[96 * STRT];  // v transposed [c][row]              (25.5 KB)

    const int t   = threadIdx.x;
    const int blk = blockIdx.x;
    const int b   = blk >> 8;        // batch
    const int win = blk & 255;
    const int wh  = win >> 4, ww = win & 15;

    // ---- stage x window into LDS (rolled coords: src h = (wh*8+r+4)%128) ----
    for (int i = t; i < 64 * 96; i += 256) {
        int row = i / 96, ch = i - row * 96;
        int r = row >> 3, c = row & 7;
        int h = (wh * 8 + r + 4) & 127;
        int w = (ww * 8 + c + 4) & 127;
        xs[row * STRX + ch] = x[(((b * 128 + h) * 128 + w) * 96) + ch];
    }
    __syncthreads();

    // ---- K,V GEMM: lane = token row, wave owns 48 of the 192 k/v columns ----
    {
        const int wv  = __builtin_amdgcn_readfirstlane(t >> 6);
        const int row = t & 63;
        for (int chunk = 0; chunk < 4; ++chunk) {
            const int col0 = 96 + wv * 48 + chunk * 12;  // global qkv col (96..288)
            float acc[12];
            #pragma unroll
            for (int j = 0; j < 12; ++j) acc[j] = qkv_b[col0 + j];
            for (int ch = 0; ch < 96; ++ch) {
                float xv = xs[row * STRX + ch];
                #pragma unroll
                for (int j = 0; j < 12; ++j)
                    acc[j] = fmaf(xv, qkv_w[(col0 + j) * 96 + ch], acc[j]);
            }
            #pragma unroll
            for (int j = 0; j < 12; ++j) {
                int colg = col0 + j;
                if (colg < 192) kt[(colg - 96) * STRT + row] = acc[j];
                else            vt[(colg - 192) * STRT + row] = acc[j];
            }
        }
    }

    // ---- per-thread q for own (head, qrow): threads 0..191 ----
    const int head = __builtin_amdgcn_readfirstlane(t >> 6);  // 0..2 for active threads
    const int qrow = t & 63;
    float qreg[32];
    __syncthreads();  // kt/vt visible; xs still holds x-window
    if (t < 192) {
        #pragma unroll
        for (int dc = 0; dc < 32; ++dc) qreg[dc] = qkv_b[head * 32 + dc];
        for (int ch = 0; ch < 96; ++ch) {
            float xv = xs[qrow * STRX + ch];
            #pragma unroll
            for (int dc = 0; dc < 32; ++dc)
                qreg[dc] = fmaf(xv, qkv_w[(head * 32 + dc) * 96 + ch], qreg[dc]);
        }
        #pragma unroll
        for (int dc = 0; dc < 32; ++dc) qreg[dc] *= 0.17677669529663687f;  // 1/sqrt(32)
    }
    __syncthreads();  // all q-phase xs reads done before attention overwrites xs

    // ---- attention: thread = (head, qrow), scores in registers ----
    if (t < 192) {
        float s[64];
        #pragma unroll
        for (int j = 0; j < 64; ++j) s[j] = 0.f;
        #pragma unroll
        for (int dc = 0; dc < 32; ++dc) {
            float qv = qreg[dc];
            const float4* kp = (const float4*)&kt[(head * 32 + dc) * STRT];
            #pragma unroll
            for (int j4 = 0; j4 < 16; ++j4) {
                float4 k4 = kp[j4];
                s[4 * j4 + 0] = fmaf(qv, k4.x, s[4 * j4 + 0]);
                s[4 * j4 + 1] = fmaf(qv, k4.y, s[4 * j4 + 1]);
                s[4 * j4 + 2] = fmaf(qv, k4.z, s[4 * j4 + 2]);
                s[4 * j4 + 3] = fmaf(qv, k4.w, s[4 * j4 + 3]);
            }
        }
        // rel_bias + shifted-window mask (regions: rows <120,<124,else in shifted coords)
        const int bh = (wh == 15), bw = (ww == 15);
        const int qrr = bh ? (((qrow >> 3) < 4) ? 1 : 2) : 0;
        const int qcc = bw ? (((qrow & 7) < 4) ? 1 : 2) : 0;
        float mx = -1e30f;
        const float4* rbp = (const float4*)&rel_bias[(head * 64 + qrow) * 64];
        #pragma unroll
        for (int j4 = 0; j4 < 16; ++j4) {
            float4 rb = rbp[j4];
            #pragma unroll
            for (int i = 0; i < 4; ++i) {
                int j = 4 * j4 + i;
                float rbv = (i == 0) ? rb.x : (i == 1) ? rb.y : (i == 2) ? rb.z : rb.w;
                int jrr = bh ? (((j >> 3) < 4) ? 1 : 2) : 0;
                int jcc = bw ? (((j & 7) < 4) ? 1 : 2) : 0;
                float m = ((jrr != qrr) || (jcc != qcc)) ? -100.f : 0.f;
                float val = s[j] + rbv + m;
                s[j] = val;
                mx = fmaxf(mx, val);
            }
        }
        float sum = 0.f;
        #pragma unroll
        for (int j = 0; j < 64; ++j) { float e = __expf(s[j] - mx); s[j] = e; sum += e; }
        float inv = 1.f / sum;
        #pragma unroll
        for (int dc = 0; dc < 32; ++dc) {
            const float4* vp = (const float4*)&vt[(head * 32 + dc) * STRT];
            float a = 0.f;
            #pragma unroll
            for (int j4 = 0; j4 < 16; ++j4) {
                float4 v4 = vp[j4];
                a = fmaf(s[4 * j4 + 0], v4.x, a);
                a = fmaf(s[4 * j4 + 1], v4.y, a);
                a = fmaf(s[4 * j4 + 2], v4.z, a);
                a = fmaf(s[4 * j4 + 3], v4.w, a);
            }
            xs[qrow * STRX + head * 32 + dc] = a * inv;  // attn output (row-major C layout)
        }
    }
    __syncthreads();  // attn-out in xs; kt free for proj staging

    // ---- proj GEMM: lane = row, wave owns 24 of 96 output cols ----
    {
        const int wv  = __builtin_amdgcn_readfirstlane(t >> 6);
        const int row = t & 63;
        for (int chunk = 0; chunk < 2; ++chunk) {
            const int col0 = wv * 24 + chunk * 12;
            float acc[12];
            #pragma unroll
            for (int j = 0; j < 12; ++j) acc[j] = proj_b[col0 + j];
            for (int cc = 0; cc < 96; ++cc) {
                float xv = xs[row * STRX + cc];
                #pragma unroll
                for (int j = 0; j < 12; ++j)
                    acc[j] = fmaf(xv, proj_w[(col0 + j) * 96 + cc], acc[j]);
            }
            #pragma unroll
            for (int j = 0; j < 12; ++j)
                kt[row * STRX + col0 + j] = acc[j];  // reuse kt as out staging
        }
    }
    __syncthreads();

    // ---- coalesced store with roll-back (same (h,w) as the gather) ----
    for (int i = t; i < 64 * 96; i += 256) {
        int row = i / 96, ch = i - row * 96;
        int r = row >> 3, c = row & 7;
        int h = (wh * 8 + r + 4) & 127;
        int w = (ww * 8 + c + 4) & 127;
        out[(((b * 128 + h) * 128 + w) * 96) + ch] = kt[row * STRX + ch];
    }
}

extern "C" void kernel_launch(void* const* d_in, const int* in_sizes, int n_in,
                              void* d_out, int out_size, void* d_ws, size_t ws_size,
                              hipStream_t stream) {
    const float* x        = (const float*)d_in[0];
    const float* qkv_w    = (const float*)d_in[1];
    const float* qkv_b    = (const float*)d_in[2];
    const float* proj_w   = (const float*)d_in[3];
    const float* proj_b   = (const float*)d_in[4];
    const float* rel_bias = (const float*)d_in[5];
    float* out = (float*)d_out;

    dim3 grid(4096), block(256);
    hipLaunchKernelGGL(swin_fused, grid, block, 0, stream,
                       x, qkv_w, qkv_b, proj_w, proj_b, rel_bias, out);
}

// Round 2
// 314.226 us; speedup vs baseline: 3.3892x; 3.3892x over previous
//
#include <hip/hip_runtime.h>

// Swin shifted-window attention, fused, bf16 MFMA (16x16x32).
// B=16 H=W=128 C=96 NH=3 d=32 WS=8 SS=4 -> L=64 tokens/window, 4096 blocks.
// Fragment layouts (verified on gfx950, see cdna_hip_programming.md §3):
//   A: lane holds A[m=lane&15][k=quad*8+j]      (16B contiguous row-major read)
//   B: lane holds B[k=quad*8+j][n=lane&15]      (16B contiguous read of B^T rows)
//   C/D: lane holds (row=quad*4+reg, col=lane&15)

typedef __attribute__((ext_vector_type(8))) short short8;
typedef __attribute__((ext_vector_type(4))) float f32x4;

#define XST 104   // xs row stride (bf16): 208B, 16B-aligned, 2-way banks (free)
#define QST 40    // q/k row stride: 80B, 16B-aligned, 2-way banks
#define VST 72    // vt row stride: 144B, 16B-aligned, 2-way banks
#define PST 72    // p row stride

__device__ __forceinline__ unsigned short f2b(float f) {
    union { float f; unsigned u; } v; v.f = f;
    unsigned r = v.u + 0x7fffu + ((v.u >> 16) & 1u);   // RNE
    return (unsigned short)(r >> 16);
}

__device__ __forceinline__ short8 packw8(const float* __restrict__ p) {
    float4 a = *(const float4*)p;
    float4 c = *(const float4*)(p + 4);
    short8 r;
    r[0] = (short)f2b(a.x); r[1] = (short)f2b(a.y);
    r[2] = (short)f2b(a.z); r[3] = (short)f2b(a.w);
    r[4] = (short)f2b(c.x); r[5] = (short)f2b(c.y);
    r[6] = (short)f2b(c.z); r[7] = (short)f2b(c.w);
    return r;
}

__global__ __launch_bounds__(256, 2) void swin_mfma(
    const float* __restrict__ x,
    const float* __restrict__ qkv_w,
    const float* __restrict__ qkv_b,
    const float* __restrict__ proj_w,
    const float* __restrict__ proj_b,
    const float* __restrict__ rel_bias,
    float* __restrict__ out)
{
    __shared__ __align__(16) unsigned short xs[64 * XST];      // 13.0 KB: x-window bf16; later attn-out
    __shared__ __align__(16) unsigned short qb[3 * 64 * QST];  // 15.0 KB: q row-major, pre-scaled
    __shared__ __align__(16) unsigned short kb[3 * 64 * QST];  // 15.0 KB: k row-major
    __shared__ __align__(16) unsigned short vt[3 * 32 * VST];  // 13.5 KB: v transposed [d][row]
    __shared__ __align__(16) unsigned short pb[64 * PST];      //  9.0 KB: P, wave-private strips

    const int t    = threadIdx.x;
    const int wv   = t >> 6;          // wave id 0..3 = m-strip owner
    const int lane = t & 63;
    const int quad = lane >> 4;
    const int l16  = lane & 15;
    const int m0   = wv * 16;

    const int blk = blockIdx.x;
    const int bb  = blk >> 8;
    const int win = blk & 255;
    const int wh  = win >> 4, ww = win & 15;

    // ---- stage x window -> bf16 LDS (rolled coords) ----
    for (int idx = t; idx < 1536; idx += 256) {
        int row = idx / 24;
        int c4  = idx - row * 24;
        int r = row >> 3, c = row & 7;
        int gh = (wh * 8 + r + 4) & 127;
        int gw = (ww * 8 + c + 4) & 127;
        float4 v = *(const float4*)&x[(((bb * 128 + gh) * 128 + gw) * 96) + c4 * 4];
        ushort4 pk;
        pk.x = f2b(v.x); pk.y = f2b(v.y); pk.z = f2b(v.z); pk.w = f2b(v.w);
        *(ushort4*)&xs[row * XST + c4 * 4] = pk;
    }
    __syncthreads();

    // ---- QKV GEMM: 64x288 = (4 m-tiles) x (18 n-tiles) x (3 k-steps) ----
    {
        short8 af[4][3];
        #pragma unroll
        for (int mt = 0; mt < 4; ++mt)
            #pragma unroll
            for (int ks = 0; ks < 3; ++ks)
                af[mt][ks] = *(const short8*)&xs[(mt * 16 + l16) * XST + ks * 32 + quad * 8];

        for (int nt = wv; nt < 18; nt += 4) {
            const int n0 = nt * 16;
            float bias = qkv_b[n0 + l16];
            f32x4 acc[4];
            #pragma unroll
            for (int mt = 0; mt < 4; ++mt) acc[mt] = (f32x4){bias, bias, bias, bias};
            #pragma unroll
            for (int ks = 0; ks < 3; ++ks) {
                short8 bf = packw8(qkv_w + (n0 + l16) * 96 + ks * 32 + quad * 8);
                #pragma unroll
                for (int mt = 0; mt < 4; ++mt)
                    acc[mt] = __builtin_amdgcn_mfma_f32_16x16x32_bf16(af[mt][ks], bf, acc[mt], 0, 0, 0);
            }
            if (nt < 6) {            // Q (pre-scaled by 1/sqrt(32))
                int col = n0 + l16; int h = col >> 5; int d = col & 31;
                #pragma unroll
                for (int mt = 0; mt < 4; ++mt)
                    #pragma unroll
                    for (int r = 0; r < 4; ++r)
                        qb[(h * 64 + mt * 16 + quad * 4 + r) * QST + d] =
                            f2b(acc[mt][r] * 0.17677669529663687f);
            } else if (nt < 12) {    // K row-major
                int col = n0 - 96 + l16; int h = col >> 5; int d = col & 31;
                #pragma unroll
                for (int mt = 0; mt < 4; ++mt)
                    #pragma unroll
                    for (int r = 0; r < 4; ++r)
                        kb[(h * 64 + mt * 16 + quad * 4 + r) * QST + d] = f2b(acc[mt][r]);
            } else {                 // V transposed [d][row], packed 8B stores
                int col = n0 - 192 + l16; int h = col >> 5; int d = col & 31;
                #pragma unroll
                for (int mt = 0; mt < 4; ++mt) {
                    ushort4 pk;
                    pk.x = f2b(acc[mt][0]); pk.y = f2b(acc[mt][1]);
                    pk.z = f2b(acc[mt][2]); pk.w = f2b(acc[mt][3]);
                    *(ushort4*)&vt[(h * 32 + d) * VST + mt * 16 + quad * 4] = pk;
                }
            }
        }
    }
    __syncthreads();

    // ---- attention: wave wv owns rows m0..m0+15 for all heads (wave-private) ----
    {
        const bool bh = (wh == 15), bw = (ww == 15);
        int qrr[4], qcc[4];
        #pragma unroll
        for (int r = 0; r < 4; ++r) {
            int tok = m0 + quad * 4 + r;
            qrr[r] = bh ? (((tok >> 3) < 4) ? 1 : 2) : 0;
            qcc[r] = bw ? (((tok & 7) < 4) ? 1 : 2) : 0;
        }

        for (int h = 0; h < 3; ++h) {
            short8 qa = *(const short8*)&qb[(h * 64 + m0 + l16) * QST + quad * 8];
            f32x4 s[4];
            #pragma unroll
            for (int nt = 0; nt < 4; ++nt) {
                short8 kf = *(const short8*)&kb[(h * 64 + nt * 16 + l16) * QST + quad * 8];
                f32x4 z = (f32x4){0.f, 0.f, 0.f, 0.f};
                s[nt] = __builtin_amdgcn_mfma_f32_16x16x32_bf16(qa, kf, z, 0, 0, 0);
            }
            float rsum[4] = {0.f, 0.f, 0.f, 0.f};
            #pragma unroll
            for (int nt = 0; nt < 4; ++nt) {
                int jcol = nt * 16 + l16;
                int jrr = bh ? (((jcol >> 3) < 4) ? 1 : 2) : 0;
                int jcc = bw ? (((jcol & 7) < 4) ? 1 : 2) : 0;
                #pragma unroll
                for (int r = 0; r < 4; ++r) {
                    float bias = rel_bias[(h * 64 + m0 + quad * 4 + r) * 64 + jcol];
                    float mv = ((jrr != qrr[r]) || (jcc != qcc[r])) ? -100.f : 0.f;
                    float e = __expf(s[nt][r] + bias + mv);   // unmasked |s|<~3 -> no overflow
                    rsum[r] += e;
                    pb[(m0 + quad * 4 + r) * PST + jcol] = f2b(e);  // unnormalized P
                }
            }
            #pragma unroll
            for (int r = 0; r < 4; ++r) {   // row-sum across the 16-lane group
                float sv = rsum[r];
                sv += __shfl_xor(sv, 1);
                sv += __shfl_xor(sv, 2);
                sv += __shfl_xor(sv, 4);
                sv += __shfl_xor(sv, 8);
                rsum[r] = 1.0f / sv;        // deferred softmax normalization
            }
            f32x4 o0 = (f32x4){0.f, 0.f, 0.f, 0.f};
            f32x4 o1 = o0;
            #pragma unroll
            for (int kk = 0; kk < 2; ++kk) {
                short8 pa = *(const short8*)&pb[(m0 + l16) * PST + kk * 32 + quad * 8];
                short8 v0 = *(const short8*)&vt[(h * 32 + l16) * VST + kk * 32 + quad * 8];
                short8 v1 = *(const short8*)&vt[(h * 32 + 16 + l16) * VST + kk * 32 + quad * 8];
                o0 = __builtin_amdgcn_mfma_f32_16x16x32_bf16(pa, v0, o0, 0, 0, 0);
                o1 = __builtin_amdgcn_mfma_f32_16x16x32_bf16(pa, v1, o1, 0, 0, 0);
            }
            #pragma unroll
            for (int r = 0; r < 4; ++r) {   // attn-out -> xs (rows are wave-private)
                xs[(m0 + quad * 4 + r) * XST + h * 32 + l16]      = f2b(o0[r] * rsum[r]);
                xs[(m0 + quad * 4 + r) * XST + h * 32 + 16 + l16] = f2b(o1[r] * rsum[r]);
            }
        }
    }
    __syncthreads();

    // ---- proj GEMM: 64x96, wave wv does m-tile wv x (6 n-tiles) x (3 k-steps) ----
    {
        short8 pa[3];
        #pragma unroll
        for (int ks = 0; ks < 3; ++ks)
            pa[ks] = *(const short8*)&xs[(m0 + l16) * XST + ks * 32 + quad * 8];

        int rowbase[4];
        #pragma unroll
        for (int r = 0; r < 4; ++r) {
            int tok = m0 + quad * 4 + r;
            int tr = tok >> 3, tc = tok & 7;
            int gh = (wh * 8 + tr + 4) & 127;
            int gw = (ww * 8 + tc + 4) & 127;
            rowbase[r] = ((bb * 128 + gh) * 128 + gw) * 96;
        }
        for (int nt = 0; nt < 6; ++nt) {
            const int n0 = nt * 16;
            float bias = proj_b[n0 + l16];
            f32x4 acc = (f32x4){bias, bias, bias, bias};
            #pragma unroll
            for (int ks = 0; ks < 3; ++ks) {
                short8 bf = packw8(proj_w + (n0 + l16) * 96 + ks * 32 + quad * 8);
                acc = __builtin_amdgcn_mfma_f32_16x16x32_bf16(pa[ks], bf, acc, 0, 0, 0);
            }
            #pragma unroll
            for (int r = 0; r < 4; ++r)
                out[rowbase[r] + n0 + l16] = acc[r];
        }
    }
}

extern "C" void kernel_launch(void* const* d_in, const int* in_sizes, int n_in,
                              void* d_out, int out_size, void* d_ws, size_t ws_size,
                              hipStream_t stream) {
    const float* x        = (const float*)d_in[0];
    const float* qkv_w    = (const float*)d_in[1];
    const float* qkv_b    = (const float*)d_in[2];
    const float* proj_w   = (const float*)d_in[3];
    const float* proj_b   = (const float*)d_in[4];
    const float* rel_bias = (const float*)d_in[5];
    float* out = (float*)d_out;

    hipLaunchKernelGGL(swin_mfma, dim3(4096), dim3(256), 0, stream,
                       x, qkv_w, qkv_b, proj_w, proj_b, rel_bias, out);
}

// Round 3
// 291.286 us; speedup vs baseline: 3.6561x; 1.0788x over previous
//
#include <hip/hip_runtime.h>

// Swin shifted-window attention, fused, bf16 MFMA (16x16x32).
// B=16 H=W=128 C=96 NH=3 d=32 WS=8 SS=4 -> L=64 tokens/window, 4096 blocks.
// R3: qb eliminated (Q aliased into xs after A-frag preload) -> LDS 50.5 KB
//     -> 3 blocks/CU (was 2). __launch_bounds__(256,3).
// Fragment layouts (verified on gfx950):
//   A: lane holds A[m=lane&15][k=quad*8+j]      (16B contiguous row-major read)
//   B: lane holds B[k=quad*8+j][n=lane&15]      (16B contiguous read of B^T rows)
//   C/D: lane holds (row=quad*4+reg, col=lane&15)

typedef __attribute__((ext_vector_type(8))) short short8;
typedef __attribute__((ext_vector_type(4))) float f32x4;

#define XST 104   // xs row stride (bf16): 208B, 16B-aligned, 2-way banks (free)
#define QST 40    // k row stride: 80B, 16B-aligned, 2-way banks
#define VST 72    // vt row stride: 144B, 16B-aligned
#define PST 72    // p row stride

__device__ __forceinline__ unsigned short f2b(float f) {
    union { float f; unsigned u; } v; v.f = f;
    unsigned r = v.u + 0x7fffu + ((v.u >> 16) & 1u);   // RNE
    return (unsigned short)(r >> 16);
}

__device__ __forceinline__ short8 packw8(const float* __restrict__ p) {
    float4 a = *(const float4*)p;
    float4 c = *(const float4*)(p + 4);
    short8 r;
    r[0] = (short)f2b(a.x); r[1] = (short)f2b(a.y);
    r[2] = (short)f2b(a.z); r[3] = (short)f2b(a.w);
    r[4] = (short)f2b(c.x); r[5] = (short)f2b(c.y);
    r[6] = (short)f2b(c.z); r[7] = (short)f2b(c.w);
    return r;
}

__global__ __launch_bounds__(256, 3) void swin_mfma(
    const float* __restrict__ x,
    const float* __restrict__ qkv_w,
    const float* __restrict__ qkv_b,
    const float* __restrict__ proj_w,
    const float* __restrict__ proj_b,
    const float* __restrict__ rel_bias,
    float* __restrict__ out)
{
    __shared__ __align__(16) unsigned short xs[64 * XST];      // 13.0 KB: x bf16 -> Q (scaled) -> attn-out
    __shared__ __align__(16) unsigned short kb[3 * 64 * QST];  // 15.0 KB: k row-major
    __shared__ __align__(16) unsigned short vt[3 * 32 * VST];  // 13.5 KB: v transposed [d][row]
    __shared__ __align__(16) unsigned short pb[64 * PST];      //  9.0 KB: P, wave-private strips

    const int t    = threadIdx.x;
    const int wv   = t >> 6;          // wave id 0..3 = m-strip owner
    const int lane = t & 63;
    const int quad = lane >> 4;
    const int l16  = lane & 15;
    const int m0   = wv * 16;

    const int blk = blockIdx.x;
    const int bb  = blk >> 8;
    const int win = blk & 255;
    const int wh  = win >> 4, ww = win & 15;

    // ---- stage x window -> bf16 LDS (rolled coords) ----
    for (int idx = t; idx < 1536; idx += 256) {
        int row = idx / 24;
        int c4  = idx - row * 24;
        int r = row >> 3, c = row & 7;
        int gh = (wh * 8 + r + 4) & 127;
        int gw = (ww * 8 + c + 4) & 127;
        float4 v = *(const float4*)&x[(((bb * 128 + gh) * 128 + gw) * 96) + c4 * 4];
        ushort4 pk;
        pk.x = f2b(v.x); pk.y = f2b(v.y); pk.z = f2b(v.z); pk.w = f2b(v.w);
        *(ushort4*)&xs[row * XST + c4 * 4] = pk;
    }
    __syncthreads();

    // ---- preload X A-frags; then xs is dead and can hold Q ----
    short8 af[4][3];
    #pragma unroll
    for (int mt = 0; mt < 4; ++mt)
        #pragma unroll
        for (int ks = 0; ks < 3; ++ks)
            af[mt][ks] = *(const short8*)&xs[(mt * 16 + l16) * XST + ks * 32 + quad * 8];
    __syncthreads();   // all waves done reading x from xs

    // ---- QKV GEMM: 64x288 = (4 m-tiles) x (18 n-tiles) x (3 k-steps) ----
    for (int nt = wv; nt < 18; nt += 4) {
        const int n0 = nt * 16;
        float bias = qkv_b[n0 + l16];
        f32x4 acc[4];
        #pragma unroll
        for (int mt = 0; mt < 4; ++mt) acc[mt] = (f32x4){bias, bias, bias, bias};
        #pragma unroll
        for (int ks = 0; ks < 3; ++ks) {
            short8 bf = packw8(qkv_w + (n0 + l16) * 96 + ks * 32 + quad * 8);
            #pragma unroll
            for (int mt = 0; mt < 4; ++mt)
                acc[mt] = __builtin_amdgcn_mfma_f32_16x16x32_bf16(af[mt][ks], bf, acc[mt], 0, 0, 0);
        }
        if (nt < 6) {            // Q (pre-scaled by 1/sqrt(32)) -> xs[row][col], col = n0+l16
            int col = n0 + l16;
            #pragma unroll
            for (int mt = 0; mt < 4; ++mt)
                #pragma unroll
                for (int r = 0; r < 4; ++r)
                    xs[(mt * 16 + quad * 4 + r) * XST + col] =
                        f2b(acc[mt][r] * 0.17677669529663687f);
        } else if (nt < 12) {    // K row-major
            int col = n0 - 96 + l16; int h = col >> 5; int d = col & 31;
            #pragma unroll
            for (int mt = 0; mt < 4; ++mt)
                #pragma unroll
                for (int r = 0; r < 4; ++r)
                    kb[(h * 64 + mt * 16 + quad * 4 + r) * QST + d] = f2b(acc[mt][r]);
        } else {                 // V transposed [d][row], packed 8B stores
            int col = n0 - 192 + l16; int h = col >> 5; int d = col & 31;
            #pragma unroll
            for (int mt = 0; mt < 4; ++mt) {
                ushort4 pk;
                pk.x = f2b(acc[mt][0]); pk.y = f2b(acc[mt][1]);
                pk.z = f2b(acc[mt][2]); pk.w = f2b(acc[mt][3]);
                *(ushort4*)&vt[(h * 32 + d) * VST + mt * 16 + quad * 4] = pk;
            }
        }
    }
    __syncthreads();

    // ---- attention: wave wv owns rows m0..m0+15 for all heads (wave-private) ----
    {
        const bool bh = (wh == 15), bw = (ww == 15);
        int qrr[4], qcc[4];
        #pragma unroll
        for (int r = 0; r < 4; ++r) {
            int tok = m0 + quad * 4 + r;
            qrr[r] = bh ? (((tok >> 3) < 4) ? 1 : 2) : 0;
            qcc[r] = bw ? (((tok & 7) < 4) ? 1 : 2) : 0;
        }

        for (int h = 0; h < 3; ++h) {
            // Q A-frag from xs (cols h*32.. ; overwritten by O_h only after this read)
            short8 qa = *(const short8*)&xs[(m0 + l16) * XST + h * 32 + quad * 8];
            f32x4 s[4];
            #pragma unroll
            for (int nt = 0; nt < 4; ++nt) {
                short8 kf = *(const short8*)&kb[(h * 64 + nt * 16 + l16) * QST + quad * 8];
                f32x4 z = (f32x4){0.f, 0.f, 0.f, 0.f};
                s[nt] = __builtin_amdgcn_mfma_f32_16x16x32_bf16(qa, kf, z, 0, 0, 0);
            }
            float rsum[4] = {0.f, 0.f, 0.f, 0.f};
            #pragma unroll
            for (int nt = 0; nt < 4; ++nt) {
                int jcol = nt * 16 + l16;
                int jrr = bh ? (((jcol >> 3) < 4) ? 1 : 2) : 0;
                int jcc = bw ? (((jcol & 7) < 4) ? 1 : 2) : 0;
                #pragma unroll
                for (int r = 0; r < 4; ++r) {
                    float bias = rel_bias[(h * 64 + m0 + quad * 4 + r) * 64 + jcol];
                    float mv = ((jrr != qrr[r]) || (jcc != qcc[r])) ? -100.f : 0.f;
                    float e = __expf(s[nt][r] + bias + mv);   // unmasked |s|<~3 -> no overflow
                    rsum[r] += e;
                    pb[(m0 + quad * 4 + r) * PST + jcol] = f2b(e);  // unnormalized P
                }
            }
            #pragma unroll
            for (int r = 0; r < 4; ++r) {   // row-sum across the 16-lane group
                float sv = rsum[r];
                sv += __shfl_xor(sv, 1);
                sv += __shfl_xor(sv, 2);
                sv += __shfl_xor(sv, 4);
                sv += __shfl_xor(sv, 8);
                rsum[r] = 1.0f / sv;        // deferred softmax normalization
            }
            f32x4 o0 = (f32x4){0.f, 0.f, 0.f, 0.f};
            f32x4 o1 = o0;
            #pragma unroll
            for (int kk = 0; kk < 2; ++kk) {
                short8 pa = *(const short8*)&pb[(m0 + l16) * PST + kk * 32 + quad * 8];
                short8 v0 = *(const short8*)&vt[(h * 32 + l16) * VST + kk * 32 + quad * 8];
                short8 v1 = *(const short8*)&vt[(h * 32 + 16 + l16) * VST + kk * 32 + quad * 8];
                o0 = __builtin_amdgcn_mfma_f32_16x16x32_bf16(pa, v0, o0, 0, 0, 0);
                o1 = __builtin_amdgcn_mfma_f32_16x16x32_bf16(pa, v1, o1, 0, 0, 0);
            }
            #pragma unroll
            for (int r = 0; r < 4; ++r) {   // attn-out -> xs (rows wave-private, cols = head slot)
                xs[(m0 + quad * 4 + r) * XST + h * 32 + l16]      = f2b(o0[r] * rsum[r]);
                xs[(m0 + quad * 4 + r) * XST + h * 32 + 16 + l16] = f2b(o1[r] * rsum[r]);
            }
        }
    }
    __syncthreads();

    // ---- proj GEMM: 64x96, wave wv does m-tile wv x (6 n-tiles) x (3 k-steps) ----
    {
        short8 pa[3];
        #pragma unroll
        for (int ks = 0; ks < 3; ++ks)
            pa[ks] = *(const short8*)&xs[(m0 + l16) * XST + ks * 32 + quad * 8];

        int rowbase[4];
        #pragma unroll
        for (int r = 0; r < 4; ++r) {
            int tok = m0 + quad * 4 + r;
            int tr = tok >> 3, tc = tok & 7;
            int gh = (wh * 8 + tr + 4) & 127;
            int gw = (ww * 8 + tc + 4) & 127;
            rowbase[r] = ((bb * 128 + gh) * 128 + gw) * 96;
        }
        #pragma unroll
        for (int nt = 0; nt < 6; ++nt) {
            const int n0 = nt * 16;
            float bias = proj_b[n0 + l16];
            f32x4 acc = (f32x4){bias, bias, bias, bias};
            #pragma unroll
            for (int ks = 0; ks < 3; ++ks) {
                short8 bf = packw8(proj_w + (n0 + l16) * 96 + ks * 32 + quad * 8);
                acc = __builtin_amdgcn_mfma_f32_16x16x32_bf16(pa[ks], bf, acc, 0, 0, 0);
            }
            #pragma unroll
            for (int r = 0; r < 4; ++r)
                out[rowbase[r] + n0 + l16] = acc[r];
        }
    }
}

extern "C" void kernel_launch(void* const* d_in, const int* in_sizes, int n_in,
                              void* d_out, int out_size, void* d_ws, size_t ws_size,
                              hipStream_t stream) {
    const float* x        = (const float*)d_in[0];
    const float* qkv_w    = (const float*)d_in[1];
    const float* qkv_b    = (const float*)d_in[2];
    const float* proj_w   = (const float*)d_in[3];
    const float* proj_b   = (const float*)d_in[4];
    const float* rel_bias = (const float*)d_in[5];
    float* out = (float*)d_out;

    hipLaunchKernelGGL(swin_mfma, dim3(4096), dim3(256), 0, stream,
                       x, qkv_w, qkv_b, proj_w, proj_b, rel_bias, out);
}

// Round 4
// 241.698 us; speedup vs baseline: 4.4062x; 1.2052x over previous
//
#include <hip/hip_runtime.h>

// Swin shifted-window attention, fused, bf16 MFMA (16x16x32).
// B=16 H=W=128 C=96 NH=3 d=32 WS=8 SS=4 -> L=64 tokens/window, 4096 blocks.
// R4: weights pre-converted to bf16 (Q rows pre-scaled by 1/sqrt(32)) by a
//     prep kernel into d_ws -> main kernel B-frags are single dwordx4 loads.
// Fragment layouts (verified on gfx950):
//   A: lane holds A[m=lane&15][k=quad*8+j]      (16B contiguous row-major read)
//   B: lane holds B[k=quad*8+j][n=lane&15]      (16B contiguous read of B^T rows)
//   C/D: lane holds (row=quad*4+reg, col=lane&15)

typedef __attribute__((ext_vector_type(8))) short short8;
typedef __attribute__((ext_vector_type(4))) float f32x4;

#define XST 104   // xs row stride (bf16): 208B, 16B-aligned, 2-way banks (free)
#define QST 40    // k row stride: 80B, 16B-aligned, 2-way banks
#define VST 72    // vt row stride: 144B, 16B-aligned
#define PST 72    // p row stride

// ws layout (shorts unless noted):
//   [0        .. 27647]  qkv_w bf16, row-major [col][96], cols 0..95 pre-scaled
//   [27648    .. 36863]  proj_w bf16, row-major [col][96]
//   bytes 73728..74879   qkv_b fp32 (288), cols 0..95 pre-scaled
//   bytes 74880..75263   proj_b fp32 (96)
#define WS_QKVW 0
#define WS_PROJW 27648
#define WS_QKVB_BYTES 73728
#define WS_PROJB_BYTES 74880

__device__ __forceinline__ unsigned short f2b(float f) {
    union { float f; unsigned u; } v; v.f = f;
    unsigned r = v.u + 0x7fffu + ((v.u >> 16) & 1u);   // RNE
    return (unsigned short)(r >> 16);
}

__global__ void prep_weights(const float* __restrict__ qkv_w,
                             const float* __restrict__ qkv_b,
                             const float* __restrict__ proj_w,
                             const float* __restrict__ proj_b,
                             void* __restrict__ ws)
{
    unsigned short* wsh = (unsigned short*)ws;
    float* fqb = (float*)((char*)ws + WS_QKVB_BYTES);
    float* fpb = (float*)((char*)ws + WS_PROJB_BYTES);
    const float qs = 0.17677669529663687f;  // 1/sqrt(32)

    int idx = blockIdx.x * 256 + threadIdx.x;
    if (idx < 27648) {                       // qkv_w
        int col = idx / 96;
        float v = qkv_w[idx];
        if (col < 96) v *= qs;
        wsh[WS_QKVW + idx] = f2b(v);
    } else if (idx < 36864) {                // proj_w
        wsh[WS_PROJW + (idx - 27648)] = f2b(proj_w[idx - 27648]);
    } else if (idx < 37152) {                // qkv_b
        int col = idx - 36864;
        float v = qkv_b[col];
        if (col < 96) v *= qs;
        fqb[col] = v;
    } else if (idx < 37248) {                // proj_b
        fpb[idx - 37152] = proj_b[idx - 37152];
    }
}

__global__ __launch_bounds__(256, 3) void swin_mfma(
    const float* __restrict__ x,
    const float* __restrict__ rel_bias,
    const void* __restrict__ ws,
    float* __restrict__ out)
{
    const unsigned short* wqkv  = (const unsigned short*)ws + WS_QKVW;
    const unsigned short* wproj = (const unsigned short*)ws + WS_PROJW;
    const float* wqkvb = (const float*)((const char*)ws + WS_QKVB_BYTES);
    const float* wprjb = (const float*)((const char*)ws + WS_PROJB_BYTES);

    __shared__ __align__(16) unsigned short xs[64 * XST];      // 13.0 KB: x bf16 -> Q (scaled) -> attn-out
    __shared__ __align__(16) unsigned short kb[3 * 64 * QST];  // 15.0 KB: k row-major
    __shared__ __align__(16) unsigned short vt[3 * 32 * VST];  // 13.5 KB: v transposed [d][row]
    __shared__ __align__(16) unsigned short pb[64 * PST];      //  9.0 KB: P, wave-private strips

    const int t    = threadIdx.x;
    const int wv   = t >> 6;          // wave id 0..3 = m-strip owner
    const int lane = t & 63;
    const int quad = lane >> 4;
    const int l16  = lane & 15;
    const int m0   = wv * 16;

    const int blk = blockIdx.x;
    const int bb  = blk >> 8;
    const int win = blk & 255;
    const int wh  = win >> 4, ww = win & 15;

    // ---- stage x window -> bf16 LDS (rolled coords) ----
    for (int idx = t; idx < 1536; idx += 256) {
        int row = idx / 24;
        int c4  = idx - row * 24;
        int r = row >> 3, c = row & 7;
        int gh = (wh * 8 + r + 4) & 127;
        int gw = (ww * 8 + c + 4) & 127;
        float4 v = *(const float4*)&x[(((bb * 128 + gh) * 128 + gw) * 96) + c4 * 4];
        ushort4 pk;
        pk.x = f2b(v.x); pk.y = f2b(v.y); pk.z = f2b(v.z); pk.w = f2b(v.w);
        *(ushort4*)&xs[row * XST + c4 * 4] = pk;
    }
    __syncthreads();

    // ---- preload X A-frags; then xs is dead and can hold Q ----
    short8 af[4][3];
    #pragma unroll
    for (int mt = 0; mt < 4; ++mt)
        #pragma unroll
        for (int ks = 0; ks < 3; ++ks)
            af[mt][ks] = *(const short8*)&xs[(mt * 16 + l16) * XST + ks * 32 + quad * 8];
    __syncthreads();   // all waves done reading x from xs

    // ---- QKV GEMM: 64x288 = (4 m-tiles) x (18 n-tiles) x (3 k-steps) ----
    for (int nt = wv; nt < 18; nt += 4) {
        const int n0 = nt * 16;
        float bias = wqkvb[n0 + l16];
        f32x4 acc[4];
        #pragma unroll
        for (int mt = 0; mt < 4; ++mt) acc[mt] = (f32x4){bias, bias, bias, bias};
        #pragma unroll
        for (int ks = 0; ks < 3; ++ks) {
            short8 bf = *(const short8*)&wqkv[(n0 + l16) * 96 + ks * 32 + quad * 8];
            #pragma unroll
            for (int mt = 0; mt < 4; ++mt)
                acc[mt] = __builtin_amdgcn_mfma_f32_16x16x32_bf16(af[mt][ks], bf, acc[mt], 0, 0, 0);
        }
        if (nt < 6) {            // Q (already scaled via weights) -> xs[row][col]
            int col = n0 + l16;
            #pragma unroll
            for (int mt = 0; mt < 4; ++mt)
                #pragma unroll
                for (int r = 0; r < 4; ++r)
                    xs[(mt * 16 + quad * 4 + r) * XST + col] = f2b(acc[mt][r]);
        } else if (nt < 12) {    // K row-major
            int col = n0 - 96 + l16; int h = col >> 5; int d = col & 31;
            #pragma unroll
            for (int mt = 0; mt < 4; ++mt)
                #pragma unroll
                for (int r = 0; r < 4; ++r)
                    kb[(h * 64 + mt * 16 + quad * 4 + r) * QST + d] = f2b(acc[mt][r]);
        } else {                 // V transposed [d][row], packed 8B stores
            int col = n0 - 192 + l16; int h = col >> 5; int d = col & 31;
            #pragma unroll
            for (int mt = 0; mt < 4; ++mt) {
                ushort4 pk;
                pk.x = f2b(acc[mt][0]); pk.y = f2b(acc[mt][1]);
                pk.z = f2b(acc[mt][2]); pk.w = f2b(acc[mt][3]);
                *(ushort4*)&vt[(h * 32 + d) * VST + mt * 16 + quad * 4] = pk;
            }
        }
    }
    __syncthreads();

    // ---- attention: wave wv owns rows m0..m0+15 for all heads (wave-private) ----
    {
        const bool bh = (wh == 15), bw = (ww == 15);
        int qrr[4], qcc[4];
        #pragma unroll
        for (int r = 0; r < 4; ++r) {
            int tok = m0 + quad * 4 + r;
            qrr[r] = bh ? (((tok >> 3) < 4) ? 1 : 2) : 0;
            qcc[r] = bw ? (((tok & 7) < 4) ? 1 : 2) : 0;
        }

        for (int h = 0; h < 3; ++h) {
            // Q A-frag from xs (cols h*32.. ; overwritten by O_h only after this read)
            short8 qa = *(const short8*)&xs[(m0 + l16) * XST + h * 32 + quad * 8];
            f32x4 s[4];
            #pragma unroll
            for (int nt = 0; nt < 4; ++nt) {
                short8 kf = *(const short8*)&kb[(h * 64 + nt * 16 + l16) * QST + quad * 8];
                f32x4 z = (f32x4){0.f, 0.f, 0.f, 0.f};
                s[nt] = __builtin_amdgcn_mfma_f32_16x16x32_bf16(qa, kf, z, 0, 0, 0);
            }
            float rsum[4] = {0.f, 0.f, 0.f, 0.f};
            #pragma unroll
            for (int nt = 0; nt < 4; ++nt) {
                int jcol = nt * 16 + l16;
                int jrr = bh ? (((jcol >> 3) < 4) ? 1 : 2) : 0;
                int jcc = bw ? (((jcol & 7) < 4) ? 1 : 2) : 0;
                #pragma unroll
                for (int r = 0; r < 4; ++r) {
                    float bias = rel_bias[(h * 64 + m0 + quad * 4 + r) * 64 + jcol];
                    float mv = ((jrr != qrr[r]) || (jcc != qcc[r])) ? -100.f : 0.f;
                    float e = __expf(s[nt][r] + bias + mv);   // unmasked |s|<~3 -> no overflow
                    rsum[r] += e;
                    pb[(m0 + quad * 4 + r) * PST + jcol] = f2b(e);  // unnormalized P
                }
            }
            #pragma unroll
            for (int r = 0; r < 4; ++r) {   // row-sum across the 16-lane group
                float sv = rsum[r];
                sv += __shfl_xor(sv, 1);
                sv += __shfl_xor(sv, 2);
                sv += __shfl_xor(sv, 4);
                sv += __shfl_xor(sv, 8);
                rsum[r] = 1.0f / sv;        // deferred softmax normalization
            }
            f32x4 o0 = (f32x4){0.f, 0.f, 0.f, 0.f};
            f32x4 o1 = o0;
            #pragma unroll
            for (int kk = 0; kk < 2; ++kk) {
                short8 pa = *(const short8*)&pb[(m0 + l16) * PST + kk * 32 + quad * 8];
                short8 v0 = *(const short8*)&vt[(h * 32 + l16) * VST + kk * 32 + quad * 8];
                short8 v1 = *(const short8*)&vt[(h * 32 + 16 + l16) * VST + kk * 32 + quad * 8];
                o0 = __builtin_amdgcn_mfma_f32_16x16x32_bf16(pa, v0, o0, 0, 0, 0);
                o1 = __builtin_amdgcn_mfma_f32_16x16x32_bf16(pa, v1, o1, 0, 0, 0);
            }
            #pragma unroll
            for (int r = 0; r < 4; ++r) {   // attn-out -> xs (rows wave-private, cols = head slot)
                xs[(m0 + quad * 4 + r) * XST + h * 32 + l16]      = f2b(o0[r] * rsum[r]);
                xs[(m0 + quad * 4 + r) * XST + h * 32 + 16 + l16] = f2b(o1[r] * rsum[r]);
            }
        }
    }
    __syncthreads();

    // ---- proj GEMM: 64x96, wave wv does m-tile wv x (6 n-tiles) x (3 k-steps) ----
    {
        short8 pa[3];
        #pragma unroll
        for (int ks = 0; ks < 3; ++ks)
            pa[ks] = *(const short8*)&xs[(m0 + l16) * XST + ks * 32 + quad * 8];

        int rowbase[4];
        #pragma unroll
        for (int r = 0; r < 4; ++r) {
            int tok = m0 + quad * 4 + r;
            int tr = tok >> 3, tc = tok & 7;
            int gh = (wh * 8 + tr + 4) & 127;
            int gw = (ww * 8 + tc + 4) & 127;
            rowbase[r] = ((bb * 128 + gh) * 128 + gw) * 96;
        }
        #pragma unroll
        for (int nt = 0; nt < 6; ++nt) {
            const int n0 = nt * 16;
            float bias = wprjb[n0 + l16];
            f32x4 acc = (f32x4){bias, bias, bias, bias};
            #pragma unroll
            for (int ks = 0; ks < 3; ++ks) {
                short8 bf = *(const short8*)&wproj[(n0 + l16) * 96 + ks * 32 + quad * 8];
                acc = __builtin_amdgcn_mfma_f32_16x16x32_bf16(pa[ks], bf, acc, 0, 0, 0);
            }
            #pragma unroll
            for (int r = 0; r < 4; ++r)
                out[rowbase[r] + n0 + l16] = acc[r];
        }
    }
}

extern "C" void kernel_launch(void* const* d_in, const int* in_sizes, int n_in,
                              void* d_out, int out_size, void* d_ws, size_t ws_size,
                              hipStream_t stream) {
    const float* x        = (const float*)d_in[0];
    const float* qkv_w    = (const float*)d_in[1];
    const float* qkv_b    = (const float*)d_in[2];
    const float* proj_w   = (const float*)d_in[3];
    const float* proj_b   = (const float*)d_in[4];
    const float* rel_bias = (const float*)d_in[5];
    float* out = (float*)d_out;

    hipLaunchKernelGGL(prep_weights, dim3(146), dim3(256), 0, stream,
                       qkv_w, qkv_b, proj_w, proj_b, d_ws);
    hipLaunchKernelGGL(swin_mfma, dim3(4096), dim3(256), 0, stream,
                       x, rel_bias, (const void*)d_ws, out);
}